// Round 8
// baseline (601.431 us; speedup 1.0000x reference)
//
#include <hip/hip_runtime.h>

#define N_NODES 16384
#define N_EDGES 8192
#define MAXD 32
#define NODE_CAP 64

#define GEMM_BLKS 512
#define PE_BLKS 256
#define SCAN_BLKS 8192
#define SCAN_T (SCAN_BLKS * 256u)      // 2,097,152 threads
// H = 134,217,728 floats = 33,554,432 float4 = 16 f4/thread

// ---- scan one uint4 of H at flat float4-index i ----
__device__ __forceinline__ void scan_u4(int* __restrict__ edge_cnt,
    int* __restrict__ edge_nodes, int* __restrict__ node_cnt,
    int* __restrict__ node_edges, uint4 x, unsigned i)
{
    if (!(x.x | x.y | x.z | x.w)) return;
    unsigned base = i * 4u;
    int n  = (int)(base >> 13);          // 8192 floats per H row
    int e0 = (int)(base & 8191u);
    int m = (x.x ? 1 : 0) | (x.y ? 2 : 0) | (x.z ? 4 : 0) | (x.w ? 8 : 0);
    int np = atomicAdd(&node_cnt[n], __popc(m));
    if (x.x) { int p = atomicAdd(&edge_cnt[e0+0], 1); if (p < MAXD) edge_nodes[(e0+0)*MAXD+p] = n;
               if (np < NODE_CAP) node_edges[n*NODE_CAP+np] = e0+0; ++np; }
    if (x.y) { int p = atomicAdd(&edge_cnt[e0+1], 1); if (p < MAXD) edge_nodes[(e0+1)*MAXD+p] = n;
               if (np < NODE_CAP) node_edges[n*NODE_CAP+np] = e0+1; ++np; }
    if (x.z) { int p = atomicAdd(&edge_cnt[e0+2], 1); if (p < MAXD) edge_nodes[(e0+2)*MAXD+p] = n;
               if (np < NODE_CAP) node_edges[n*NODE_CAP+np] = e0+2; ++np; }
    if (x.w) { int p = atomicAdd(&edge_cnt[e0+3], 1); if (p < MAXD) edge_nodes[(e0+3)*MAXD+p] = n;
               if (np < NODE_CAP) node_edges[n*NODE_CAP+np] = e0+3; ++np; }
}

// ---- PROBE: R5-style scan (4096 blocks x 32 f4/thread, 4-deep unroll-1 batches) ----
// Writes to dummy buffers; timed twice per replay to measure T_scanR5 via dur_us.
__global__ __launch_bounds__(256) void probe_scan_k(const float* __restrict__ H,
    int* __restrict__ edge_cnt, int* __restrict__ edge_nodes,
    int* __restrict__ node_cnt, int* __restrict__ node_edges)
{
    const unsigned g = blockIdx.x * 256u + threadIdx.x;     // [0, 2^20)
    const unsigned T = 4096u * 256u;                        // 1,048,576
    const uint4* H4 = (const uint4*)H;
#pragma unroll 1
    for (int it = 0; it < 32; it += 4) {
        unsigned i0 = (unsigned)(it + 0) * T + g;
        unsigned i1 = (unsigned)(it + 1) * T + g;
        unsigned i2 = (unsigned)(it + 2) * T + g;
        unsigned i3 = (unsigned)(it + 3) * T + g;
        uint4 x0 = H4[i0];
        uint4 x1 = H4[i1];
        uint4 x2 = H4[i2];
        uint4 x3 = H4[i3];
        scan_u4(edge_cnt, edge_nodes, node_cnt, node_edges, x0, i0);
        scan_u4(edge_cnt, edge_nodes, node_cnt, node_edges, x1, i1);
        scan_u4(edge_cnt, edge_nodes, node_cnt, node_edges, x2, i2);
        scan_u4(edge_cnt, edge_nodes, node_cnt, node_edges, x3, i3);
    }
}

// ---------------- phase 1: vsrc GEMM (no LDS) ∥ pe ∥ H scan (R7 structure) ----------------
__global__ __launch_bounds__(256) void phase1_k(
    const float* __restrict__ v, const float* __restrict__ Wv,
    const float* __restrict__ ef, const float* __restrict__ We,
    const float* __restrict__ H,
    int* __restrict__ edge_cnt, int* __restrict__ edge_nodes,
    int* __restrict__ node_cnt, int* __restrict__ node_edges,
    float* __restrict__ vsrc, float* __restrict__ pe)
{
    const int b = blockIdx.x, tid = threadIdx.x;
    if (b < GEMM_BLKS) {
        const int row0 = b * 32;
        const int r  = tid >> 4;
        const int c0 = (tid & 15) * 8;
        const float4* A4 = (const float4*)v;
        const float4* B4 = (const float4*)Wv;
        float acc[2][8];
#pragma unroll
        for (int i = 0; i < 2; ++i)
#pragma unroll
            for (int j = 0; j < 8; ++j) acc[i][j] = 0.f;
#pragma unroll 4
        for (int k4 = 0; k4 < 32; ++k4) {
            float4 a0 = A4[(size_t)(row0 + r) * 32 + k4];
            float4 a1 = A4[(size_t)(row0 + r + 16) * 32 + k4];
#pragma unroll
            for (int kk = 0; kk < 4; ++kk) {
                int k = k4 * 4 + kk;
                float4 b0 = B4[k * 32 + (c0 >> 2)];
                float4 b1 = B4[k * 32 + (c0 >> 2) + 1];
                float av0 = kk == 0 ? a0.x : kk == 1 ? a0.y : kk == 2 ? a0.z : a0.w;
                float av1 = kk == 0 ? a1.x : kk == 1 ? a1.y : kk == 2 ? a1.z : a1.w;
                acc[0][0] = fmaf(av0, b0.x, acc[0][0]); acc[0][1] = fmaf(av0, b0.y, acc[0][1]);
                acc[0][2] = fmaf(av0, b0.z, acc[0][2]); acc[0][3] = fmaf(av0, b0.w, acc[0][3]);
                acc[0][4] = fmaf(av0, b1.x, acc[0][4]); acc[0][5] = fmaf(av0, b1.y, acc[0][5]);
                acc[0][6] = fmaf(av0, b1.z, acc[0][6]); acc[0][7] = fmaf(av0, b1.w, acc[0][7]);
                acc[1][0] = fmaf(av1, b0.x, acc[1][0]); acc[1][1] = fmaf(av1, b0.y, acc[1][1]);
                acc[1][2] = fmaf(av1, b0.z, acc[1][2]); acc[1][3] = fmaf(av1, b0.w, acc[1][3]);
                acc[1][4] = fmaf(av1, b1.x, acc[1][4]); acc[1][5] = fmaf(av1, b1.y, acc[1][5]);
                acc[1][6] = fmaf(av1, b1.z, acc[1][6]); acc[1][7] = fmaf(av1, b1.w, acc[1][7]);
            }
        }
#pragma unroll
        for (int i = 0; i < 2; ++i) {
            int row = row0 + r + i * 16;
            float4 o0 = {acc[i][0], acc[i][1], acc[i][2], acc[i][3]};
            float4 o1 = {acc[i][4], acc[i][5], acc[i][6], acc[i][7]};
            *(float4*)&vsrc[(size_t)row * 128 + c0]     = o0;
            *(float4*)&vsrc[(size_t)row * 128 + c0 + 4] = o1;
        }
    } else if (b < GEMM_BLKS + PE_BLKS) {
        int base = (b - GEMM_BLKS) * 512 + tid;
#pragma unroll
        for (int t = 0; t < 2; ++t) {
            int g = base + t * 256;
            int n = g >> 3, h = g & 7;
            const float4* ef4 = (const float4*)ef + n * 16;
            float p = 0.f;
#pragma unroll
            for (int d4 = 0; d4 < 16; ++d4) {
                float4 x = ef4[d4];
                p += x.x * We[(d4 * 4 + 0) * 8 + h] + x.y * We[(d4 * 4 + 1) * 8 + h]
                   + x.z * We[(d4 * 4 + 2) * 8 + h] + x.w * We[(d4 * 4 + 3) * 8 + h];
            }
            pe[g] = p;
        }
    } else {
        const unsigned g = (unsigned)(b - GEMM_BLKS - PE_BLKS) * 256u + tid;
        const unsigned S = SCAN_T;
        const uint4* H4 = (const uint4*)H;
        uint4 a0, a1, a2, a3, b0, b1, b2, b3;
        a0 = H4[g +  0*S]; a1 = H4[g +  1*S]; a2 = H4[g +  2*S]; a3 = H4[g +  3*S];
        b0 = H4[g +  4*S]; b1 = H4[g +  5*S]; b2 = H4[g +  6*S]; b3 = H4[g +  7*S];
        scan_u4(edge_cnt, edge_nodes, node_cnt, node_edges, a0, g + 0*S);
        scan_u4(edge_cnt, edge_nodes, node_cnt, node_edges, a1, g + 1*S);
        scan_u4(edge_cnt, edge_nodes, node_cnt, node_edges, a2, g + 2*S);
        scan_u4(edge_cnt, edge_nodes, node_cnt, node_edges, a3, g + 3*S);
        a0 = H4[g +  8*S]; a1 = H4[g +  9*S]; a2 = H4[g + 10*S]; a3 = H4[g + 11*S];
        scan_u4(edge_cnt, edge_nodes, node_cnt, node_edges, b0, g + 4*S);
        scan_u4(edge_cnt, edge_nodes, node_cnt, node_edges, b1, g + 5*S);
        scan_u4(edge_cnt, edge_nodes, node_cnt, node_edges, b2, g + 6*S);
        scan_u4(edge_cnt, edge_nodes, node_cnt, node_edges, b3, g + 7*S);
        b0 = H4[g + 12*S]; b1 = H4[g + 13*S]; b2 = H4[g + 14*S]; b3 = H4[g + 15*S];
        scan_u4(edge_cnt, edge_nodes, node_cnt, node_edges, a0, g +  8*S);
        scan_u4(edge_cnt, edge_nodes, node_cnt, node_edges, a1, g +  9*S);
        scan_u4(edge_cnt, edge_nodes, node_cnt, node_edges, a2, g + 10*S);
        scan_u4(edge_cnt, edge_nodes, node_cnt, node_edges, a3, g + 11*S);
        scan_u4(edge_cnt, edge_nodes, node_cnt, node_edges, b0, g + 12*S);
        scan_u4(edge_cnt, edge_nodes, node_cnt, node_edges, b1, g + 13*S);
        scan_u4(edge_cnt, edge_nodes, node_cnt, node_edges, b2, g + 14*S);
        scan_u4(edge_cnt, edge_nodes, node_cnt, node_edges, b3, g + 15*S);
    }
}

// ---------------- eexp[e,h] = exp(be[h] + sum_j pe[n_j,h]) ----------------
__global__ __launch_bounds__(256) void eexp_k(const int* __restrict__ edge_cnt,
    const int* __restrict__ edge_nodes, const float* __restrict__ pe,
    const float* __restrict__ be, float* __restrict__ eexp)
{
    int g = blockIdx.x * 256 + threadIdx.x;   // (e,h)
    int e = g >> 3, h = g & 7;
    int cnt = min(edge_cnt[e], MAXD);
    float s = be[h];
    for (int j = 0; j < cnt; ++j) s += pe[edge_nodes[e * MAXD + j] * 8 + h];
    eexp[g] = __expf(s);      // softmax shift-invariant; |s| = O(1) -> safe
}

// ---------------- s_arr[n,h] = 1/(sum_{e in n} eexp[e,h] + eps) ----------------
__global__ __launch_bounds__(256) void z_k(const int* __restrict__ node_cnt,
    const int* __restrict__ node_edges, const float* __restrict__ eexp,
    float* __restrict__ s_arr)
{
    int g = blockIdx.x * 256 + threadIdx.x;   // (n,h)
    int n = g >> 3, h = g & 7;
    int cnt = min(node_cnt[n], NODE_CAP);
    float z = 0.f;
    for (int i = 0; i < cnt; ++i) z += eexp[node_edges[n * NODE_CAP + i] * 8 + h];
    s_arr[g] = 1.0f / (z + 1e-10f);
}

// ---- fused msg+Wo: Ms = attn-weighted vsrc sums (LDS), msgo = Ms @ Wo ----
__global__ __launch_bounds__(256) void msgwo_k(const int* __restrict__ edge_cnt,
    const int* __restrict__ edge_nodes, const float* __restrict__ eexp,
    const float* __restrict__ s_arr, const float* __restrict__ vsrc,
    const float* __restrict__ Wo, float* __restrict__ msgo)
{
    __shared__ float Ms[32][128];
    __shared__ float Bs[32][128];
    const int tid = threadIdx.x;
    const int e0  = blockIdx.x * 32;

#pragma unroll
    for (int i = 0; i < 4; ++i) {
        int p = i * 256 + tid;
        int le = p >> 5, c4 = p & 31, h = c4 >> 2;
        int e = e0 + le;
        int cnt = min(edge_cnt[e], MAXD);
        float eh = eexp[e * 8 + h];
        const float4* v4 = (const float4*)vsrc;
        float4 acc = {0.f, 0.f, 0.f, 0.f};
        for (int j = 0; j < cnt; ++j) {
            int n = edge_nodes[e * MAXD + j];
            float t = s_arr[n * 8 + h];
            float4 x = v4[(size_t)n * 32 + c4];
            acc.x = fmaf(t, x.x, acc.x); acc.y = fmaf(t, x.y, acc.y);
            acc.z = fmaf(t, x.z, acc.z); acc.w = fmaf(t, x.w, acc.w);
        }
        acc.x *= eh; acc.y *= eh; acc.z *= eh; acc.w *= eh;
        *(float4*)&Ms[le][c4 * 4] = acc;
    }
    __syncthreads();

    const int r  = tid >> 4;
    const int c0 = (tid & 15) * 8;
    float acc[2][8];
#pragma unroll
    for (int i = 0; i < 2; ++i)
#pragma unroll
        for (int j = 0; j < 8; ++j) acc[i][j] = 0.f;

    for (int kt = 0; kt < 128; kt += 32) {
#pragma unroll
        for (int u0 = 0; u0 < 4; ++u0) {
            int u = u0 * 256 + tid;
            int kk = u >> 5, cc = (u & 31) * 4;
            *(float4*)&Bs[kk][cc] = *(const float4*)&Wo[(kt + kk) * 128 + cc];
        }
        __syncthreads();
#pragma unroll
        for (int k = 0; k < 32; ++k) {
            float a0 = Ms[r][kt + k];
            float a1 = Ms[r + 16][kt + k];
#pragma unroll
            for (int j = 0; j < 8; ++j) {
                float b = Bs[k][c0 + j];
                acc[0][j] = fmaf(a0, b, acc[0][j]);
                acc[1][j] = fmaf(a1, b, acc[1][j]);
            }
        }
        __syncthreads();
    }
#pragma unroll
    for (int i = 0; i < 2; ++i) {
        int row = e0 + r + i * 16;
#pragma unroll
        for (int j = 0; j < 8; ++j) msgo[(size_t)row * 128 + c0 + j] = acc[i][j];
    }
}

// ---- final fused: h = q + sum_{e in n} msgo[e] ; out = h + relu(h@W1+b1)@W2 + b2 ----
__global__ __launch_bounds__(256) void ffn_agg_k(const float* __restrict__ q,
    const int* __restrict__ node_cnt, const int* __restrict__ node_edges,
    const float* __restrict__ msgo, const float* __restrict__ W1,
    const float* __restrict__ b1, const float* __restrict__ W2,
    const float* __restrict__ b2, float* __restrict__ out)
{
    __shared__ float Hs[32][128];
    __shared__ char dyn[49152];
    float (*B1s)[256] = (float(*)[256])dyn;
    float (*Ts)[256]  = (float(*)[256])dyn;
    float (*B2s)[128] = (float(*)[128])(dyn + 32768);

    const int tid  = threadIdx.x;
    const int row0 = blockIdx.x * 32;

    {
        int r = tid >> 3, lc = tid & 7;
        int n = row0 + r;
        const float4* q4 = (const float4*)q;
        const float4* m4 = (const float4*)msgo;
        float4 acc[4];
#pragma unroll
        for (int u = 0; u < 4; ++u) acc[u] = q4[(size_t)n * 32 + lc + 8 * u];
        int cnt = min(node_cnt[n], NODE_CAP);
        for (int i = 0; i < cnt; ++i) {
            int e = node_edges[n * NODE_CAP + i];
#pragma unroll
            for (int u = 0; u < 4; ++u) {
                float4 x = m4[(size_t)e * 32 + lc + 8 * u];
                acc[u].x += x.x; acc[u].y += x.y; acc[u].z += x.z; acc[u].w += x.w;
            }
        }
#pragma unroll
        for (int u = 0; u < 4; ++u)
            *(float4*)&Hs[r][(lc + 8 * u) * 4] = acc[u];
    }
    __syncthreads();

    const int r  = tid >> 4;
    const int cb = tid & 15;

    float acc[2][16];
#pragma unroll
    for (int i = 0; i < 2; ++i)
#pragma unroll
        for (int j = 0; j < 16; ++j) acc[i][j] = 0.f;

    for (int kt = 0; kt < 128; kt += 32) {
#pragma unroll
        for (int u0 = 0; u0 < 8; ++u0) {
            int u = u0 * 256 + tid;
            int kk = u >> 6, cc = (u & 63) * 4;
            *(float4*)&B1s[kk][cc] = *(const float4*)&W1[(kt + kk) * 256 + cc];
        }
        __syncthreads();
#pragma unroll
        for (int k = 0; k < 32; ++k) {
            float a0 = Hs[r][kt + k], a1 = Hs[r + 16][kt + k];
#pragma unroll
            for (int j = 0; j < 16; ++j) {
                float b = B1s[k][cb * 16 + j];
                acc[0][j] = fmaf(a0, b, acc[0][j]);
                acc[1][j] = fmaf(a1, b, acc[1][j]);
            }
        }
        __syncthreads();
    }
#pragma unroll
    for (int i = 0; i < 2; ++i)
#pragma unroll
        for (int j = 0; j < 16; ++j) {
            int col = cb * 16 + j;
            Ts[r + i * 16][col] = fmaxf(acc[i][j] + b1[col], 0.f);
        }

    float acc2[2][8];
#pragma unroll
    for (int i = 0; i < 2; ++i)
#pragma unroll
        for (int j = 0; j < 8; ++j) acc2[i][j] = 0.f;

    for (int kt = 0; kt < 256; kt += 32) {
#pragma unroll
        for (int u0 = 0; u0 < 4; ++u0) {
            int u = u0 * 256 + tid;
            int kk = u >> 5, cc = (u & 31) * 4;
            *(float4*)&B2s[kk][cc] = *(const float4*)&W2[(kt + kk) * 128 + cc];
        }
        __syncthreads();
#pragma unroll
        for (int k = 0; k < 32; ++k) {
            float a0 = Ts[r][kt + k], a1 = Ts[r + 16][kt + k];
#pragma unroll
            for (int j = 0; j < 8; ++j) {
                float b = B2s[k][cb * 8 + j];
                acc2[0][j] = fmaf(a0, b, acc2[0][j]);
                acc2[1][j] = fmaf(a1, b, acc2[1][j]);
            }
        }
        __syncthreads();
    }
#pragma unroll
    for (int i = 0; i < 2; ++i) {
        int row = row0 + r + i * 16;
#pragma unroll
        for (int j = 0; j < 8; ++j) {
            int col = cb * 8 + j;
            out[(size_t)row * 128 + col] = Hs[r + i * 16][col] + acc2[i][j] + b2[col];
        }
    }
}

extern "C" void kernel_launch(void* const* d_in, const int* in_sizes, int n_in,
                              void* d_out, int out_size, void* d_ws, size_t ws_size,
                              hipStream_t stream)
{
    const float* q  = (const float*)d_in[0];
    // d_in[1] = k : dead (per-node q·k dot is segment-constant, cancels in softmax)
    const float* v  = (const float*)d_in[2];
    const float* ef = (const float*)d_in[3];
    const float* H  = (const float*)d_in[4];
    // d_in[5] = Wq, d_in[6] = Wk : dead
    const float* Wv = (const float*)d_in[7];
    const float* We = (const float*)d_in[8];
    const float* be = (const float*)d_in[9];
    const float* Wo = (const float*)d_in[10];
    const float* W1 = (const float*)d_in[11];
    const float* b1 = (const float*)d_in[12];
    const float* W2 = (const float*)d_in[13];
    const float* b2 = (const float*)d_in[14];
    float* out = (float*)d_out;

    char* w = (char*)d_ws;
    auto carve = [&](size_t bytes) -> void* {
        void* p = (void*)w;
        w += (bytes + 255) & ~(size_t)255;
        return p;
    };
    // zeroed region: real counters + probe dummy counters (contiguous)
    int* edge_cnt    = (int*)carve(N_EDGES * 4);
    int* node_cnt    = (int*)carve(N_NODES * 4);
    int* p_edge_cnt  = (int*)carve(N_EDGES * 4);
    int* p_node_cnt  = (int*)carve(N_NODES * 4);
    size_t zero_bytes = (size_t)(w - (char*)d_ws);
    int* edge_nodes   = (int*)carve((size_t)N_EDGES * MAXD * 4);
    int* node_edges   = (int*)carve((size_t)N_NODES * NODE_CAP * 4);
    int* p_edge_nodes = (int*)carve((size_t)N_EDGES * MAXD * 4);
    int* p_node_edges = (int*)carve((size_t)N_NODES * NODE_CAP * 4);
    float* pe       = (float*)carve((size_t)N_NODES * 8 * 4);
    float* eexp     = (float*)carve((size_t)N_EDGES * 8 * 4);
    float* s_arr    = (float*)carve((size_t)N_NODES * 8 * 4);
    float* vsrc     = (float*)carve((size_t)N_NODES * 128 * 4);
    float* msgo     = (float*)carve((size_t)N_EDGES * 128 * 4);
    (void)ws_size; (void)in_sizes; (void)n_in; (void)out_size;

    hipMemsetAsync(d_ws, 0, zero_bytes, stream);

    // --- timing probes: 2x R5-style scan into dummy buffers ---
    probe_scan_k<<<4096, 256, 0, stream>>>(H, p_edge_cnt, p_edge_nodes,
                                           p_node_cnt, p_node_edges);
    probe_scan_k<<<4096, 256, 0, stream>>>(H, p_edge_cnt, p_edge_nodes,
                                           p_node_cnt, p_node_edges);

    // --- real pipeline (R7, unchanged) ---
    phase1_k<<<GEMM_BLKS + PE_BLKS + SCAN_BLKS, 256, 0, stream>>>(
        v, Wv, ef, We, H, edge_cnt, edge_nodes, node_cnt, node_edges, vsrc, pe);
    eexp_k<<<(N_EDGES * 8) / 256, 256, 0, stream>>>(edge_cnt, edge_nodes, pe, be, eexp);
    z_k<<<(N_NODES * 8) / 256, 256, 0, stream>>>(node_cnt, node_edges, eexp, s_arr);
    msgwo_k<<<N_EDGES / 32, 256, 0, stream>>>(edge_cnt, edge_nodes, eexp, s_arr,
                                              vsrc, Wo, msgo);
    ffn_agg_k<<<N_NODES / 32, 256, 0, stream>>>(q, node_cnt, node_edges, msgo,
                                                W1, b1, W2, b2, out);
}

// Round 9
// 300.820 us; speedup vs baseline: 1.9993x; 1.9993x over previous
//
#include <hip/hip_runtime.h>

#define N_NODES 16384
#define N_EDGES 8192
#define MAXD 32
#define NODE_CAP 64

#define SCAN_BLKS 4096
#define GEMM_BLKS 512
#define PE_BLKS 256
#define SCAN_T (SCAN_BLKS * 256u)      // 1,048,576 threads, 32 f4/thread

// ---- scan one uint4 of H at flat float4-index i ----
__device__ __forceinline__ void scan_u4(int* __restrict__ edge_cnt,
    int* __restrict__ edge_nodes, int* __restrict__ node_cnt,
    int* __restrict__ node_edges, uint4 x, unsigned i)
{
    if (!(x.x | x.y | x.z | x.w)) return;
    unsigned base = i * 4u;
    int n  = (int)(base >> 13);          // 8192 floats per H row
    int e0 = (int)(base & 8191u);
    int m = (x.x ? 1 : 0) | (x.y ? 2 : 0) | (x.z ? 4 : 0) | (x.w ? 8 : 0);
    int np = atomicAdd(&node_cnt[n], __popc(m));
    if (x.x) { int p = atomicAdd(&edge_cnt[e0+0], 1); if (p < MAXD) edge_nodes[(e0+0)*MAXD+p] = n;
               if (np < NODE_CAP) node_edges[n*NODE_CAP+np] = e0+0; ++np; }
    if (x.y) { int p = atomicAdd(&edge_cnt[e0+1], 1); if (p < MAXD) edge_nodes[(e0+1)*MAXD+p] = n;
               if (np < NODE_CAP) node_edges[n*NODE_CAP+np] = e0+1; ++np; }
    if (x.z) { int p = atomicAdd(&edge_cnt[e0+2], 1); if (p < MAXD) edge_nodes[(e0+2)*MAXD+p] = n;
               if (np < NODE_CAP) node_edges[n*NODE_CAP+np] = e0+2; ++np; }
    if (x.w) { int p = atomicAdd(&edge_cnt[e0+3], 1); if (p < MAXD) edge_nodes[(e0+3)*MAXD+p] = n;
               if (np < NODE_CAP) node_edges[n*NODE_CAP+np] = e0+3; ++np; }
}

// ---------------- phase 1: H scan FIRST, then vsrc GEMM ∥ pe backfill the tail ----------------
__global__ __launch_bounds__(256) void phase1_k(
    const float* __restrict__ v, const float* __restrict__ Wv,
    const float* __restrict__ ef, const float* __restrict__ We,
    const float* __restrict__ H,
    int* __restrict__ edge_cnt, int* __restrict__ edge_nodes,
    int* __restrict__ node_cnt, int* __restrict__ node_edges,
    float* __restrict__ vsrc, float* __restrict__ pe)
{
    const int b = blockIdx.x, tid = threadIdx.x;
    if (b < SCAN_BLKS) {
        // probe-validated scan: 32 f4/thread, 4-deep batches, unroll 1
        const unsigned g = (unsigned)b * 256u + tid;
        const unsigned T = SCAN_T;
        const uint4* H4 = (const uint4*)H;
#pragma unroll 1
        for (int it = 0; it < 32; it += 4) {
            unsigned i0 = (unsigned)(it + 0) * T + g;
            unsigned i1 = (unsigned)(it + 1) * T + g;
            unsigned i2 = (unsigned)(it + 2) * T + g;
            unsigned i3 = (unsigned)(it + 3) * T + g;
            uint4 x0 = H4[i0];
            uint4 x1 = H4[i1];
            uint4 x2 = H4[i2];
            uint4 x3 = H4[i3];
            scan_u4(edge_cnt, edge_nodes, node_cnt, node_edges, x0, i0);
            scan_u4(edge_cnt, edge_nodes, node_cnt, node_edges, x1, i1);
            scan_u4(edge_cnt, edge_nodes, node_cnt, node_edges, x2, i2);
            scan_u4(edge_cnt, edge_nodes, node_cnt, node_edges, x3, i3);
        }
    } else if (b < SCAN_BLKS + GEMM_BLKS) {
        // vsrc = v @ Wv : 32 rows/block, Wv (64 KB) broadcast through caches
        const int row0 = (b - SCAN_BLKS) * 32;
        const int r  = tid >> 4;
        const int c0 = (tid & 15) * 8;
        const float4* A4 = (const float4*)v;
        const float4* B4 = (const float4*)Wv;
        float acc[2][8];
#pragma unroll
        for (int i = 0; i < 2; ++i)
#pragma unroll
            for (int j = 0; j < 8; ++j) acc[i][j] = 0.f;
#pragma unroll 4
        for (int k4 = 0; k4 < 32; ++k4) {
            float4 a0 = A4[(size_t)(row0 + r) * 32 + k4];
            float4 a1 = A4[(size_t)(row0 + r + 16) * 32 + k4];
#pragma unroll
            for (int kk = 0; kk < 4; ++kk) {
                int k = k4 * 4 + kk;
                float4 b0 = B4[k * 32 + (c0 >> 2)];
                float4 b1 = B4[k * 32 + (c0 >> 2) + 1];
                float av0 = kk == 0 ? a0.x : kk == 1 ? a0.y : kk == 2 ? a0.z : a0.w;
                float av1 = kk == 0 ? a1.x : kk == 1 ? a1.y : kk == 2 ? a1.z : a1.w;
                acc[0][0] = fmaf(av0, b0.x, acc[0][0]); acc[0][1] = fmaf(av0, b0.y, acc[0][1]);
                acc[0][2] = fmaf(av0, b0.z, acc[0][2]); acc[0][3] = fmaf(av0, b0.w, acc[0][3]);
                acc[0][4] = fmaf(av0, b1.x, acc[0][4]); acc[0][5] = fmaf(av0, b1.y, acc[0][5]);
                acc[0][6] = fmaf(av0, b1.z, acc[0][6]); acc[0][7] = fmaf(av0, b1.w, acc[0][7]);
                acc[1][0] = fmaf(av1, b0.x, acc[1][0]); acc[1][1] = fmaf(av1, b0.y, acc[1][1]);
                acc[1][2] = fmaf(av1, b0.z, acc[1][2]); acc[1][3] = fmaf(av1, b0.w, acc[1][3]);
                acc[1][4] = fmaf(av1, b1.x, acc[1][4]); acc[1][5] = fmaf(av1, b1.y, acc[1][5]);
                acc[1][6] = fmaf(av1, b1.z, acc[1][6]); acc[1][7] = fmaf(av1, b1.w, acc[1][7]);
            }
        }
#pragma unroll
        for (int i = 0; i < 2; ++i) {
            int row = row0 + r + i * 16;
            float4 o0 = {acc[i][0], acc[i][1], acc[i][2], acc[i][3]};
            float4 o1 = {acc[i][4], acc[i][5], acc[i][6], acc[i][7]};
            *(float4*)&vsrc[(size_t)row * 128 + c0]     = o0;
            *(float4*)&vsrc[(size_t)row * 128 + c0 + 4] = o1;
        }
    } else {
        // pe[n,h] = ef[n,:] @ We[:,h], 2 items/thread
        int base = (b - SCAN_BLKS - GEMM_BLKS) * 512 + tid;
#pragma unroll
        for (int t = 0; t < 2; ++t) {
            int g = base + t * 256;
            int n = g >> 3, h = g & 7;
            const float4* ef4 = (const float4*)ef + n * 16;
            float p = 0.f;
#pragma unroll
            for (int d4 = 0; d4 < 16; ++d4) {
                float4 x = ef4[d4];
                p += x.x * We[(d4 * 4 + 0) * 8 + h] + x.y * We[(d4 * 4 + 1) * 8 + h]
                   + x.z * We[(d4 * 4 + 2) * 8 + h] + x.w * We[(d4 * 4 + 3) * 8 + h];
            }
            pe[g] = p;
        }
    }
}

// ---------------- eexp[e,h] = exp(be[h] + sum_j pe[n_j,h])  (4-way ILP) ----------------
__global__ __launch_bounds__(256) void eexp_k(const int* __restrict__ edge_cnt,
    const int* __restrict__ edge_nodes, const float* __restrict__ pe,
    const float* __restrict__ be, float* __restrict__ eexp)
{
    int g = blockIdx.x * 256 + threadIdx.x;   // (e,h)
    int e = g >> 3, h = g & 7;
    int cnt = min(edge_cnt[e], MAXD);
    float s0 = be[h], s1 = 0.f, s2 = 0.f, s3 = 0.f;
    int j = 0;
    for (; j + 4 <= cnt; j += 4) {
        int4 nn = *(const int4*)&edge_nodes[e * MAXD + j];
        s0 += pe[nn.x * 8 + h];
        s1 += pe[nn.y * 8 + h];
        s2 += pe[nn.z * 8 + h];
        s3 += pe[nn.w * 8 + h];
    }
    for (; j < cnt; ++j) s0 += pe[edge_nodes[e * MAXD + j] * 8 + h];
    eexp[g] = __expf((s0 + s1) + (s2 + s3));  // softmax shift-invariant; |s|=O(1) safe
}

// ---------------- s_arr[n,h] = 1/(sum_{e in n} eexp[e,h] + eps)  (4-way ILP) ----------------
__global__ __launch_bounds__(256) void z_k(const int* __restrict__ node_cnt,
    const int* __restrict__ node_edges, const float* __restrict__ eexp,
    float* __restrict__ s_arr)
{
    int g = blockIdx.x * 256 + threadIdx.x;   // (n,h)
    int n = g >> 3, h = g & 7;
    int cnt = min(node_cnt[n], NODE_CAP);
    float z0 = 0.f, z1 = 0.f, z2 = 0.f, z3 = 0.f;
    int i = 0;
    for (; i + 4 <= cnt; i += 4) {
        int4 ee = *(const int4*)&node_edges[n * NODE_CAP + i];
        z0 += eexp[ee.x * 8 + h];
        z1 += eexp[ee.y * 8 + h];
        z2 += eexp[ee.z * 8 + h];
        z3 += eexp[ee.w * 8 + h];
    }
    for (; i < cnt; ++i) z0 += eexp[node_edges[n * NODE_CAP + i] * 8 + h];
    s_arr[g] = 1.0f / (((z0 + z1) + (z2 + z3)) + 1e-10f);
}

// ---- fused msg+Wo: 16 edges/block (512 blocks), Ms in LDS, msgo = Ms @ Wo ----
// LDS = Ms 8 KB + Bs 16 KB = 24 KB
__global__ __launch_bounds__(256) void msgwo_k(const int* __restrict__ edge_cnt,
    const int* __restrict__ edge_nodes, const float* __restrict__ eexp,
    const float* __restrict__ s_arr, const float* __restrict__ vsrc,
    const float* __restrict__ Wo, float* __restrict__ msgo)
{
    __shared__ float Ms[16][128];
    __shared__ float Bs[32][128];
    const int tid = threadIdx.x;
    const int e0  = blockIdx.x * 16;

    // msg rows into Ms: 512 (le,c4) items, 2 per thread; 4-way ILP on members
#pragma unroll
    for (int i = 0; i < 2; ++i) {
        int p = i * 256 + tid;
        int le = p >> 5, c4 = p & 31, h = c4 >> 2;
        int e = e0 + le;
        int cnt = min(edge_cnt[e], MAXD);
        float eh = eexp[e * 8 + h];
        const float4* v4 = (const float4*)vsrc;
        float4 acc = {0.f, 0.f, 0.f, 0.f};
        int j = 0;
        for (; j + 4 <= cnt; j += 4) {
            int4 nn = *(const int4*)&edge_nodes[e * MAXD + j];
            float t0 = s_arr[nn.x * 8 + h];
            float t1 = s_arr[nn.y * 8 + h];
            float t2 = s_arr[nn.z * 8 + h];
            float t3 = s_arr[nn.w * 8 + h];
            float4 x0 = v4[(size_t)nn.x * 32 + c4];
            float4 x1 = v4[(size_t)nn.y * 32 + c4];
            float4 x2 = v4[(size_t)nn.z * 32 + c4];
            float4 x3 = v4[(size_t)nn.w * 32 + c4];
            acc.x = fmaf(t0, x0.x, acc.x); acc.y = fmaf(t0, x0.y, acc.y);
            acc.z = fmaf(t0, x0.z, acc.z); acc.w = fmaf(t0, x0.w, acc.w);
            acc.x = fmaf(t1, x1.x, acc.x); acc.y = fmaf(t1, x1.y, acc.y);
            acc.z = fmaf(t1, x1.z, acc.z); acc.w = fmaf(t1, x1.w, acc.w);
            acc.x = fmaf(t2, x2.x, acc.x); acc.y = fmaf(t2, x2.y, acc.y);
            acc.z = fmaf(t2, x2.z, acc.z); acc.w = fmaf(t2, x2.w, acc.w);
            acc.x = fmaf(t3, x3.x, acc.x); acc.y = fmaf(t3, x3.y, acc.y);
            acc.z = fmaf(t3, x3.z, acc.z); acc.w = fmaf(t3, x3.w, acc.w);
        }
        for (; j < cnt; ++j) {
            int n = edge_nodes[e * MAXD + j];
            float t = s_arr[n * 8 + h];
            float4 x = v4[(size_t)n * 32 + c4];
            acc.x = fmaf(t, x.x, acc.x); acc.y = fmaf(t, x.y, acc.y);
            acc.z = fmaf(t, x.z, acc.z); acc.w = fmaf(t, x.w, acc.w);
        }
        acc.x *= eh; acc.y *= eh; acc.z *= eh; acc.w *= eh;
        *(float4*)&Ms[le][c4 * 4] = acc;
    }
    __syncthreads();

    // msgo[e0..e0+16][:] = Ms @ Wo   (16 rows, 128 cols)
    const int r  = tid >> 4;          // 0..15
    const int c0 = (tid & 15) * 8;
    float acc[8];
#pragma unroll
    for (int j = 0; j < 8; ++j) acc[j] = 0.f;

    for (int kt = 0; kt < 128; kt += 32) {
#pragma unroll
        for (int u0 = 0; u0 < 4; ++u0) {              // Bs: 32x128 = 1024 float4
            int u = u0 * 256 + tid;
            int kk = u >> 5, cc = (u & 31) * 4;
            *(float4*)&Bs[kk][cc] = *(const float4*)&Wo[(kt + kk) * 128 + cc];
        }
        __syncthreads();
#pragma unroll
        for (int k = 0; k < 32; ++k) {
            float a = Ms[r][kt + k];
#pragma unroll
            for (int j = 0; j < 8; ++j)
                acc[j] = fmaf(a, Bs[k][c0 + j], acc[j]);
        }
        __syncthreads();
    }
#pragma unroll
    for (int j = 0; j < 8; ++j) msgo[(size_t)(e0 + r) * 128 + c0 + j] = acc[j];
}

// ---- final fused: h = q + sum_{e in n} msgo[e] ; out = h + relu(h@W1+b1)@W2 + b2 ----
__global__ __launch_bounds__(256) void ffn_agg_k(const float* __restrict__ q,
    const int* __restrict__ node_cnt, const int* __restrict__ node_edges,
    const float* __restrict__ msgo, const float* __restrict__ W1,
    const float* __restrict__ b1, const float* __restrict__ W2,
    const float* __restrict__ b2, float* __restrict__ out)
{
    __shared__ float Hs[32][128];
    __shared__ char dyn[49152];
    float (*B1s)[256] = (float(*)[256])dyn;
    float (*Ts)[256]  = (float(*)[256])dyn;
    float (*B2s)[128] = (float(*)[128])(dyn + 32768);

    const int tid  = threadIdx.x;
    const int row0 = blockIdx.x * 32;

    {   // aggregate: Hs = q + sum msgo, 4-way ILP on edges
        int r = tid >> 3, lc = tid & 7;
        int n = row0 + r;
        const float4* q4 = (const float4*)q;
        const float4* m4 = (const float4*)msgo;
        float4 acc[4];
#pragma unroll
        for (int u = 0; u < 4; ++u) acc[u] = q4[(size_t)n * 32 + lc + 8 * u];
        int cnt = min(node_cnt[n], NODE_CAP);
        int i = 0;
        for (; i + 4 <= cnt; i += 4) {
            int4 ee = *(const int4*)&node_edges[n * NODE_CAP + i];
#pragma unroll
            for (int u = 0; u < 4; ++u) {
                float4 x0 = m4[(size_t)ee.x * 32 + lc + 8 * u];
                float4 x1 = m4[(size_t)ee.y * 32 + lc + 8 * u];
                float4 x2 = m4[(size_t)ee.z * 32 + lc + 8 * u];
                float4 x3 = m4[(size_t)ee.w * 32 + lc + 8 * u];
                acc[u].x += (x0.x + x1.x) + (x2.x + x3.x);
                acc[u].y += (x0.y + x1.y) + (x2.y + x3.y);
                acc[u].z += (x0.z + x1.z) + (x2.z + x3.z);
                acc[u].w += (x0.w + x1.w) + (x2.w + x3.w);
            }
        }
        for (; i < cnt; ++i) {
            int e = node_edges[n * NODE_CAP + i];
#pragma unroll
            for (int u = 0; u < 4; ++u) {
                float4 x = m4[(size_t)e * 32 + lc + 8 * u];
                acc[u].x += x.x; acc[u].y += x.y; acc[u].z += x.z; acc[u].w += x.w;
            }
        }
#pragma unroll
        for (int u = 0; u < 4; ++u)
            *(float4*)&Hs[r][(lc + 8 * u) * 4] = acc[u];
    }
    __syncthreads();

    const int r  = tid >> 4;
    const int cb = tid & 15;

    // phase A: T = relu(h @ W1 + b1), KT=32
    float acc[2][16];
#pragma unroll
    for (int i = 0; i < 2; ++i)
#pragma unroll
        for (int j = 0; j < 16; ++j) acc[i][j] = 0.f;

    for (int kt = 0; kt < 128; kt += 32) {
#pragma unroll
        for (int u0 = 0; u0 < 8; ++u0) {
            int u = u0 * 256 + tid;
            int kk = u >> 6, cc = (u & 63) * 4;
            *(float4*)&B1s[kk][cc] = *(const float4*)&W1[(kt + kk) * 256 + cc];
        }
        __syncthreads();
#pragma unroll
        for (int k = 0; k < 32; ++k) {
            float a0 = Hs[r][kt + k], a1 = Hs[r + 16][kt + k];
#pragma unroll
            for (int j = 0; j < 16; ++j) {
                float b = B1s[k][cb * 16 + j];
                acc[0][j] = fmaf(a0, b, acc[0][j]);
                acc[1][j] = fmaf(a1, b, acc[1][j]);
            }
        }
        __syncthreads();
    }
#pragma unroll
    for (int i = 0; i < 2; ++i)
#pragma unroll
        for (int j = 0; j < 16; ++j) {
            int col = cb * 16 + j;
            Ts[r + i * 16][col] = fmaxf(acc[i][j] + b1[col], 0.f);
        }

    // phase B: out = h + T @ W2 + b2, KT=32
    float acc2[2][8];
#pragma unroll
    for (int i = 0; i < 2; ++i)
#pragma unroll
        for (int j = 0; j < 8; ++j) acc2[i][j] = 0.f;

    for (int kt = 0; kt < 256; kt += 32) {
#pragma unroll
        for (int u0 = 0; u0 < 4; ++u0) {
            int u = u0 * 256 + tid;
            int kk = u >> 5, cc = (u & 31) * 4;
            *(float4*)&B2s[kk][cc] = *(const float4*)&W2[(kt + kk) * 128 + cc];
        }
        __syncthreads();
#pragma unroll
        for (int k = 0; k < 32; ++k) {
            float a0 = Ts[r][kt + k], a1 = Ts[r + 16][kt + k];
#pragma unroll
            for (int j = 0; j < 8; ++j) {
                float b = B2s[k][cb * 8 + j];
                acc2[0][j] = fmaf(a0, b, acc2[0][j]);
                acc2[1][j] = fmaf(a1, b, acc2[1][j]);
            }
        }
        __syncthreads();
    }
#pragma unroll
    for (int i = 0; i < 2; ++i) {
        int row = row0 + r + i * 16;
#pragma unroll
        for (int j = 0; j < 8; ++j) {
            int col = cb * 8 + j;
            out[(size_t)row * 128 + col] = Hs[r + i * 16][col] + acc2[i][j] + b2[col];
        }
    }
}

extern "C" void kernel_launch(void* const* d_in, const int* in_sizes, int n_in,
                              void* d_out, int out_size, void* d_ws, size_t ws_size,
                              hipStream_t stream)
{
    const float* q  = (const float*)d_in[0];
    // d_in[1] = k : dead (per-node q·k dot is segment-constant, cancels in softmax)
    const float* v  = (const float*)d_in[2];
    const float* ef = (const float*)d_in[3];
    const float* H  = (const float*)d_in[4];
    // d_in[5] = Wq, d_in[6] = Wk : dead
    const float* Wv = (const float*)d_in[7];
    const float* We = (const float*)d_in[8];
    const float* be = (const float*)d_in[9];
    const float* Wo = (const float*)d_in[10];
    const float* W1 = (const float*)d_in[11];
    const float* b1 = (const float*)d_in[12];
    const float* W2 = (const float*)d_in[13];
    const float* b2 = (const float*)d_in[14];
    float* out = (float*)d_out;

    char* w = (char*)d_ws;
    auto carve = [&](size_t bytes) -> void* {
        void* p = (void*)w;
        w += (bytes + 255) & ~(size_t)255;
        return p;
    };
    int* edge_cnt   = (int*)carve(N_EDGES * 4);                    // zeroed
    int* node_cnt   = (int*)carve(N_NODES * 4);                    // zeroed
    size_t zero_bytes = (size_t)(w - (char*)d_ws);
    int* edge_nodes = (int*)carve((size_t)N_EDGES * MAXD * 4);
    int* node_edges = (int*)carve((size_t)N_NODES * NODE_CAP * 4);
    float* pe       = (float*)carve((size_t)N_NODES * 8 * 4);
    float* eexp     = (float*)carve((size_t)N_EDGES * 8 * 4);
    float* s_arr    = (float*)carve((size_t)N_NODES * 8 * 4);
    float* vsrc     = (float*)carve((size_t)N_NODES * 128 * 4);
    float* msgo     = (float*)carve((size_t)N_EDGES * 128 * 4);
    (void)ws_size; (void)in_sizes; (void)n_in; (void)out_size;

    hipMemsetAsync(d_ws, 0, zero_bytes, stream);

    phase1_k<<<SCAN_BLKS + GEMM_BLKS + PE_BLKS, 256, 0, stream>>>(
        v, Wv, ef, We, H, edge_cnt, edge_nodes, node_cnt, node_edges, vsrc, pe);
    eexp_k<<<(N_EDGES * 8) / 256, 256, 0, stream>>>(edge_cnt, edge_nodes, pe, be, eexp);
    z_k<<<(N_NODES * 8) / 256, 256, 0, stream>>>(node_cnt, node_edges, eexp, s_arr);
    msgwo_k<<<N_EDGES / 16, 256, 0, stream>>>(edge_cnt, edge_nodes, eexp, s_arr,
                                              vsrc, Wo, msgo);
    ffn_agg_k<<<N_NODES / 32, 256, 0, stream>>>(q, node_cnt, node_edges, msgo,
                                                W1, b1, W2, b2, out);
}

// Round 10
// 294.902 us; speedup vs baseline: 2.0394x; 1.0201x over previous
//
#include <hip/hip_runtime.h>

#define N_NODES 16384
#define N_EDGES 8192
#define MAXD 32
#define NODE_CAP 64

#define SCAN_BLKS 4096
#define GEMM_BLKS 512
#define PE_BLKS 256
#define SCAN_T (SCAN_BLKS * 256u)      // 1,048,576 threads, 32 f4/thread

// ---- bf16 helpers (RNE) ----
__device__ __forceinline__ unsigned f2b(float f) {
    unsigned u = __float_as_uint(f);
    return (u + 0x7FFFu + ((u >> 16) & 1u)) >> 16;
}
__device__ __forceinline__ unsigned pack2(float lo, float hi) {
    return f2b(lo) | (f2b(hi) << 16);
}
__device__ __forceinline__ float blo(unsigned w) { return __uint_as_float(w << 16); }
__device__ __forceinline__ float bhi(unsigned w) { return __uint_as_float(w & 0xFFFF0000u); }

// ---- scan one uint4 of H at flat float4-index i ----
__device__ __forceinline__ void scan_u4(int* __restrict__ edge_cnt,
    int* __restrict__ edge_nodes, int* __restrict__ node_cnt,
    int* __restrict__ node_edges, uint4 x, unsigned i)
{
    if (!(x.x | x.y | x.z | x.w)) return;
    unsigned base = i * 4u;
    int n  = (int)(base >> 13);          // 8192 floats per H row
    int e0 = (int)(base & 8191u);
    int m = (x.x ? 1 : 0) | (x.y ? 2 : 0) | (x.z ? 4 : 0) | (x.w ? 8 : 0);
    int np = atomicAdd(&node_cnt[n], __popc(m));
    if (x.x) { int p = atomicAdd(&edge_cnt[e0+0], 1); if (p < MAXD) edge_nodes[(e0+0)*MAXD+p] = n;
               if (np < NODE_CAP) node_edges[n*NODE_CAP+np] = e0+0; ++np; }
    if (x.y) { int p = atomicAdd(&edge_cnt[e0+1], 1); if (p < MAXD) edge_nodes[(e0+1)*MAXD+p] = n;
               if (np < NODE_CAP) node_edges[n*NODE_CAP+np] = e0+1; ++np; }
    if (x.z) { int p = atomicAdd(&edge_cnt[e0+2], 1); if (p < MAXD) edge_nodes[(e0+2)*MAXD+p] = n;
               if (np < NODE_CAP) node_edges[n*NODE_CAP+np] = e0+2; ++np; }
    if (x.w) { int p = atomicAdd(&edge_cnt[e0+3], 1); if (p < MAXD) edge_nodes[(e0+3)*MAXD+p] = n;
               if (np < NODE_CAP) node_edges[n*NODE_CAP+np] = e0+3; ++np; }
}

// ---------------- phase 1: H scan (8-deep pipelined) FIRST, GEMM/pe backfill ----------------
__global__ __launch_bounds__(256) void phase1_k(
    const float* __restrict__ v, const float* __restrict__ Wv,
    const float* __restrict__ ef, const float* __restrict__ We,
    const float* __restrict__ H,
    int* __restrict__ edge_cnt, int* __restrict__ edge_nodes,
    int* __restrict__ node_cnt, int* __restrict__ node_edges,
    float* __restrict__ vsrc, float* __restrict__ pe)
{
    const int b = blockIdx.x, tid = threadIdx.x;
    if (b < SCAN_BLKS) {
        const unsigned g = (unsigned)b * 256u + tid;
        const unsigned T = SCAN_T;
        const uint4* H4 = (const uint4*)H;
        uint4 a0, a1, a2, a3, b0, b1, b2, b3;
        a0 = H4[g + 0u*T]; a1 = H4[g + 1u*T]; a2 = H4[g + 2u*T]; a3 = H4[g + 3u*T];
        b0 = H4[g + 4u*T]; b1 = H4[g + 5u*T]; b2 = H4[g + 6u*T]; b3 = H4[g + 7u*T];
        __builtin_amdgcn_sched_barrier(0);
#pragma unroll 1
        for (int it = 0; it < 32; it += 8) {
            scan_u4(edge_cnt, edge_nodes, node_cnt, node_edges, a0, (unsigned)(it+0)*T + g);
            scan_u4(edge_cnt, edge_nodes, node_cnt, node_edges, a1, (unsigned)(it+1)*T + g);
            scan_u4(edge_cnt, edge_nodes, node_cnt, node_edges, a2, (unsigned)(it+2)*T + g);
            scan_u4(edge_cnt, edge_nodes, node_cnt, node_edges, a3, (unsigned)(it+3)*T + g);
            if (it + 8 < 32) {
                a0 = H4[g + (unsigned)(it+ 8)*T]; a1 = H4[g + (unsigned)(it+ 9)*T];
                a2 = H4[g + (unsigned)(it+10)*T]; a3 = H4[g + (unsigned)(it+11)*T];
            }
            __builtin_amdgcn_sched_barrier(0);
            scan_u4(edge_cnt, edge_nodes, node_cnt, node_edges, b0, (unsigned)(it+4)*T + g);
            scan_u4(edge_cnt, edge_nodes, node_cnt, node_edges, b1, (unsigned)(it+5)*T + g);
            scan_u4(edge_cnt, edge_nodes, node_cnt, node_edges, b2, (unsigned)(it+6)*T + g);
            scan_u4(edge_cnt, edge_nodes, node_cnt, node_edges, b3, (unsigned)(it+7)*T + g);
            if (it + 12 < 32) {
                b0 = H4[g + (unsigned)(it+12)*T]; b1 = H4[g + (unsigned)(it+13)*T];
                b2 = H4[g + (unsigned)(it+14)*T]; b3 = H4[g + (unsigned)(it+15)*T];
            }
            __builtin_amdgcn_sched_barrier(0);
        }
    } else if (b < SCAN_BLKS + GEMM_BLKS) {
        // vsrc = v @ Wv : 32 rows/block, Wv (64 KB) broadcast through caches
        const int row0 = (b - SCAN_BLKS) * 32;
        const int r  = tid >> 4;
        const int c0 = (tid & 15) * 8;
        const float4* A4 = (const float4*)v;
        const float4* B4 = (const float4*)Wv;
        float acc[2][8];
#pragma unroll
        for (int i = 0; i < 2; ++i)
#pragma unroll
            for (int j = 0; j < 8; ++j) acc[i][j] = 0.f;
#pragma unroll 4
        for (int k4 = 0; k4 < 32; ++k4) {
            float4 a0 = A4[(size_t)(row0 + r) * 32 + k4];
            float4 a1 = A4[(size_t)(row0 + r + 16) * 32 + k4];
#pragma unroll
            for (int kk = 0; kk < 4; ++kk) {
                int k = k4 * 4 + kk;
                float4 b0 = B4[k * 32 + (c0 >> 2)];
                float4 b1 = B4[k * 32 + (c0 >> 2) + 1];
                float av0 = kk == 0 ? a0.x : kk == 1 ? a0.y : kk == 2 ? a0.z : a0.w;
                float av1 = kk == 0 ? a1.x : kk == 1 ? a1.y : kk == 2 ? a1.z : a1.w;
                acc[0][0] = fmaf(av0, b0.x, acc[0][0]); acc[0][1] = fmaf(av0, b0.y, acc[0][1]);
                acc[0][2] = fmaf(av0, b0.z, acc[0][2]); acc[0][3] = fmaf(av0, b0.w, acc[0][3]);
                acc[0][4] = fmaf(av0, b1.x, acc[0][4]); acc[0][5] = fmaf(av0, b1.y, acc[0][5]);
                acc[0][6] = fmaf(av0, b1.z, acc[0][6]); acc[0][7] = fmaf(av0, b1.w, acc[0][7]);
                acc[1][0] = fmaf(av1, b0.x, acc[1][0]); acc[1][1] = fmaf(av1, b0.y, acc[1][1]);
                acc[1][2] = fmaf(av1, b0.z, acc[1][2]); acc[1][3] = fmaf(av1, b0.w, acc[1][3]);
                acc[1][4] = fmaf(av1, b1.x, acc[1][4]); acc[1][5] = fmaf(av1, b1.y, acc[1][5]);
                acc[1][6] = fmaf(av1, b1.z, acc[1][6]); acc[1][7] = fmaf(av1, b1.w, acc[1][7]);
            }
        }
#pragma unroll
        for (int i = 0; i < 2; ++i) {
            int row = row0 + r + i * 16;
            float4 o0 = {acc[i][0], acc[i][1], acc[i][2], acc[i][3]};
            float4 o1 = {acc[i][4], acc[i][5], acc[i][6], acc[i][7]};
            *(float4*)&vsrc[(size_t)row * 128 + c0]     = o0;
            *(float4*)&vsrc[(size_t)row * 128 + c0 + 4] = o1;
        }
    } else {
        // pe[n,h] = ef[n,:] @ We[:,h], 2 items/thread
        int base = (b - SCAN_BLKS - GEMM_BLKS) * 512 + tid;
#pragma unroll
        for (int t = 0; t < 2; ++t) {
            int g = base + t * 256;
            int n = g >> 3, h = g & 7;
            const float4* ef4 = (const float4*)ef + n * 16;
            float p = 0.f;
#pragma unroll
            for (int d4 = 0; d4 < 16; ++d4) {
                float4 x = ef4[d4];
                p += x.x * We[(d4 * 4 + 0) * 8 + h] + x.y * We[(d4 * 4 + 1) * 8 + h]
                   + x.z * We[(d4 * 4 + 2) * 8 + h] + x.w * We[(d4 * 4 + 3) * 8 + h];
            }
            pe[g] = p;
        }
    }
}

// ---------------- eexp[e,h] = exp(be[h] + sum_j pe[n_j,h])  (4-way ILP) ----------------
__global__ __launch_bounds__(256) void eexp_k(const int* __restrict__ edge_cnt,
    const int* __restrict__ edge_nodes, const float* __restrict__ pe,
    const float* __restrict__ be, float* __restrict__ eexp)
{
    int g = blockIdx.x * 256 + threadIdx.x;   // (e,h)
    int e = g >> 3, h = g & 7;
    int cnt = min(edge_cnt[e], MAXD);
    float s0 = be[h], s1 = 0.f, s2 = 0.f, s3 = 0.f;
    int j = 0;
    for (; j + 4 <= cnt; j += 4) {
        int4 nn = *(const int4*)&edge_nodes[e * MAXD + j];
        s0 += pe[nn.x * 8 + h];
        s1 += pe[nn.y * 8 + h];
        s2 += pe[nn.z * 8 + h];
        s3 += pe[nn.w * 8 + h];
    }
    for (; j < cnt; ++j) s0 += pe[edge_nodes[e * MAXD + j] * 8 + h];
    eexp[g] = __expf((s0 + s1) + (s2 + s3));  // softmax shift-invariant; |s|=O(1) safe
}

// ---- zu_k: z[n,h] = sum eexp; u[n, h*16..+16) = (1/(z+eps)) * vsrc, stored bf16 ----
__global__ __launch_bounds__(256) void zu_k(const int* __restrict__ node_cnt,
    const int* __restrict__ node_edges, const float* __restrict__ eexp,
    const float* __restrict__ vsrc, uint4* __restrict__ u4)
{
    int g = blockIdx.x * 256 + threadIdx.x;   // (n,h)
    int n = g >> 3, h = g & 7;
    int cnt = min(node_cnt[n], NODE_CAP);
    float z0 = 0.f, z1 = 0.f, z2 = 0.f, z3 = 0.f;
    int i = 0;
    for (; i + 4 <= cnt; i += 4) {
        int4 ee = *(const int4*)&node_edges[n * NODE_CAP + i];
        z0 += eexp[ee.x * 8 + h];
        z1 += eexp[ee.y * 8 + h];
        z2 += eexp[ee.z * 8 + h];
        z3 += eexp[ee.w * 8 + h];
    }
    for (; i < cnt; ++i) z0 += eexp[node_edges[n * NODE_CAP + i] * 8 + h];
    float s = 1.0f / (((z0 + z1) + (z2 + z3)) + 1e-10f);

    const float4* v4 = (const float4*)vsrc + (size_t)n * 32 + h * 4;
    float4 x0 = v4[0], x1 = v4[1], x2 = v4[2], x3 = v4[3];
    uint4 w0, w1;
    w0.x = pack2(s * x0.x, s * x0.y); w0.y = pack2(s * x0.z, s * x0.w);
    w0.z = pack2(s * x1.x, s * x1.y); w0.w = pack2(s * x1.z, s * x1.w);
    w1.x = pack2(s * x2.x, s * x2.y); w1.y = pack2(s * x2.z, s * x2.w);
    w1.z = pack2(s * x3.x, s * x3.y); w1.w = pack2(s * x3.z, s * x3.w);
    u4[(size_t)n * 16 + h * 2]     = w0;
    u4[(size_t)n * 16 + h * 2 + 1] = w1;
}

// ---- fused msg+Wo: msg[e,c] = eexp[e,h] * sum_j u[n_j,c]; msgo = msg @ Wo (bf16 out) ----
// 16 edges/block (512 blocks); LDS = Ms 8 KB + Bs 16 KB = 24 KB
__global__ __launch_bounds__(256) void msgwo_k(const int* __restrict__ edge_cnt,
    const int* __restrict__ edge_nodes, const float* __restrict__ eexp,
    const uint4* __restrict__ u4, const float* __restrict__ Wo,
    uint4* __restrict__ msgo4)
{
    __shared__ float Ms[16][128];
    __shared__ float Bs[32][128];
    const int tid = threadIdx.x;
    const int e0  = blockIdx.x * 16;

    {   // one (le, c8) item per thread: 8 channels, all within head h = c8>>1
        int le = tid >> 4, c8 = tid & 15;
        int e = e0 + le;
        int h = c8 >> 1;
        int cnt = min(edge_cnt[e], MAXD);
        float eh = eexp[e * 8 + h];
        float a[8];
#pragma unroll
        for (int k = 0; k < 8; ++k) a[k] = 0.f;
        int j = 0;
        for (; j + 4 <= cnt; j += 4) {
            int4 nn = *(const int4*)&edge_nodes[e * MAXD + j];
            uint4 w0 = u4[(size_t)nn.x * 16 + c8];
            uint4 w1 = u4[(size_t)nn.y * 16 + c8];
            uint4 w2 = u4[(size_t)nn.z * 16 + c8];
            uint4 w3 = u4[(size_t)nn.w * 16 + c8];
            a[0] += (blo(w0.x) + blo(w1.x)) + (blo(w2.x) + blo(w3.x));
            a[1] += (bhi(w0.x) + bhi(w1.x)) + (bhi(w2.x) + bhi(w3.x));
            a[2] += (blo(w0.y) + blo(w1.y)) + (blo(w2.y) + blo(w3.y));
            a[3] += (bhi(w0.y) + bhi(w1.y)) + (bhi(w2.y) + bhi(w3.y));
            a[4] += (blo(w0.z) + blo(w1.z)) + (blo(w2.z) + blo(w3.z));
            a[5] += (bhi(w0.z) + bhi(w1.z)) + (bhi(w2.z) + bhi(w3.z));
            a[6] += (blo(w0.w) + blo(w1.w)) + (blo(w2.w) + blo(w3.w));
            a[7] += (bhi(w0.w) + bhi(w1.w)) + (bhi(w2.w) + bhi(w3.w));
        }
        for (; j < cnt; ++j) {
            uint4 w = u4[(size_t)edge_nodes[e * MAXD + j] * 16 + c8];
            a[0] += blo(w.x); a[1] += bhi(w.x); a[2] += blo(w.y); a[3] += bhi(w.y);
            a[4] += blo(w.z); a[5] += bhi(w.z); a[6] += blo(w.w); a[7] += bhi(w.w);
        }
        float4 o0 = {a[0]*eh, a[1]*eh, a[2]*eh, a[3]*eh};
        float4 o1 = {a[4]*eh, a[5]*eh, a[6]*eh, a[7]*eh};
        *(float4*)&Ms[le][c8 * 8]     = o0;
        *(float4*)&Ms[le][c8 * 8 + 4] = o1;
    }
    __syncthreads();

    // msgo[e0..e0+16][:] = Ms @ Wo, bf16 out
    const int r  = tid >> 4;          // 0..15
    const int c0 = (tid & 15) * 8;
    float acc[8];
#pragma unroll
    for (int j = 0; j < 8; ++j) acc[j] = 0.f;

    for (int kt = 0; kt < 128; kt += 32) {
#pragma unroll
        for (int u0 = 0; u0 < 4; ++u0) {              // Bs: 32x128 = 1024 float4
            int u = u0 * 256 + tid;
            int kk = u >> 5, cc = (u & 31) * 4;
            *(float4*)&Bs[kk][cc] = *(const float4*)&Wo[(kt + kk) * 128 + cc];
        }
        __syncthreads();
#pragma unroll
        for (int k = 0; k < 32; ++k) {
            float a = Ms[r][kt + k];
#pragma unroll
            for (int j = 0; j < 8; ++j)
                acc[j] = fmaf(a, Bs[k][c0 + j], acc[j]);
        }
        __syncthreads();
    }
    uint4 w;
    w.x = pack2(acc[0], acc[1]); w.y = pack2(acc[2], acc[3]);
    w.z = pack2(acc[4], acc[5]); w.w = pack2(acc[6], acc[7]);
    msgo4[(size_t)(e0 + r) * 16 + (c0 >> 3)] = w;
}

// ---- final fused: h = q + sum_{e in n} msgo[e] ; out = h + relu(h@W1+b1)@W2 + b2 ----
__global__ __launch_bounds__(256) void ffn_agg_k(const float* __restrict__ q,
    const int* __restrict__ node_cnt, const int* __restrict__ node_edges,
    const uint4* __restrict__ msgo4, const float* __restrict__ W1,
    const float* __restrict__ b1, const float* __restrict__ W2,
    const float* __restrict__ b2, float* __restrict__ out)
{
    __shared__ float Hs[32][128];
    __shared__ char dyn[49152];
    float (*B1s)[256] = (float(*)[256])dyn;
    float (*Ts)[256]  = (float(*)[256])dyn;
    float (*B2s)[128] = (float(*)[128])(dyn + 32768);

    const int tid  = threadIdx.x;
    const int row0 = blockIdx.x * 32;

    {   // aggregate: Hs = q + sum msgo (bf16 gathers, 2-edge ILP x 2 uint4)
        int r = tid >> 3, lc = tid & 7;           // 16 channels: [lc*16, lc*16+16)
        int n = row0 + r;
        const float4* q4 = (const float4*)q + (size_t)n * 32 + lc * 4;
        float a[16];
        {
            float4 qa = q4[0], qb = q4[1], qc = q4[2], qd = q4[3];
            a[0]=qa.x; a[1]=qa.y; a[2]=qa.z; a[3]=qa.w;
            a[4]=qb.x; a[5]=qb.y; a[6]=qb.z; a[7]=qb.w;
            a[8]=qc.x; a[9]=qc.y; a[10]=qc.z; a[11]=qc.w;
            a[12]=qd.x; a[13]=qd.y; a[14]=qd.z; a[15]=qd.w;
        }
        int cnt = min(node_cnt[n], NODE_CAP);
        int i = 0;
        for (; i + 2 <= cnt; i += 2) {
            int ea = node_edges[n * NODE_CAP + i];
            int eb = node_edges[n * NODE_CAP + i + 1];
            uint4 wa0 = msgo4[(size_t)ea * 16 + lc * 2];
            uint4 wa1 = msgo4[(size_t)ea * 16 + lc * 2 + 1];
            uint4 wb0 = msgo4[(size_t)eb * 16 + lc * 2];
            uint4 wb1 = msgo4[(size_t)eb * 16 + lc * 2 + 1];
            a[0]  += blo(wa0.x) + blo(wb0.x); a[1]  += bhi(wa0.x) + bhi(wb0.x);
            a[2]  += blo(wa0.y) + blo(wb0.y); a[3]  += bhi(wa0.y) + bhi(wb0.y);
            a[4]  += blo(wa0.z) + blo(wb0.z); a[5]  += bhi(wa0.z) + bhi(wb0.z);
            a[6]  += blo(wa0.w) + blo(wb0.w); a[7]  += bhi(wa0.w) + bhi(wb0.w);
            a[8]  += blo(wa1.x) + blo(wb1.x); a[9]  += bhi(wa1.x) + bhi(wb1.x);
            a[10] += blo(wa1.y) + blo(wb1.y); a[11] += bhi(wa1.y) + bhi(wb1.y);
            a[12] += blo(wa1.z) + blo(wb1.z); a[13] += bhi(wa1.z) + bhi(wb1.z);
            a[14] += blo(wa1.w) + blo(wb1.w); a[15] += bhi(wa1.w) + bhi(wb1.w);
        }
        for (; i < cnt; ++i) {
            int e = node_edges[n * NODE_CAP + i];
            uint4 w0 = msgo4[(size_t)e * 16 + lc * 2];
            uint4 w1 = msgo4[(size_t)e * 16 + lc * 2 + 1];
            a[0]  += blo(w0.x); a[1]  += bhi(w0.x); a[2]  += blo(w0.y); a[3]  += bhi(w0.y);
            a[4]  += blo(w0.z); a[5]  += bhi(w0.z); a[6]  += blo(w0.w); a[7]  += bhi(w0.w);
            a[8]  += blo(w1.x); a[9]  += bhi(w1.x); a[10] += blo(w1.y); a[11] += bhi(w1.y);
            a[12] += blo(w1.z); a[13] += bhi(w1.z); a[14] += blo(w1.w); a[15] += bhi(w1.w);
        }
#pragma unroll
        for (int k = 0; k < 4; ++k) {
            float4 o = {a[k*4+0], a[k*4+1], a[k*4+2], a[k*4+3]};
            *(float4*)&Hs[r][lc * 16 + k * 4] = o;
        }
    }
    __syncthreads();

    const int r  = tid >> 4;
    const int cb = tid & 15;

    // phase A: T = relu(h @ W1 + b1), KT=32
    float acc[2][16];
#pragma unroll
    for (int i = 0; i < 2; ++i)
#pragma unroll
        for (int j = 0; j < 16; ++j) acc[i][j] = 0.f;

    for (int kt = 0; kt < 128; kt += 32) {
#pragma unroll
        for (int u0 = 0; u0 < 8; ++u0) {
            int u = u0 * 256 + tid;
            int kk = u >> 6, cc = (u & 63) * 4;
            *(float4*)&B1s[kk][cc] = *(const float4*)&W1[(kt + kk) * 256 + cc];
        }
        __syncthreads();
#pragma unroll
        for (int k = 0; k < 32; ++k) {
            float a0 = Hs[r][kt + k], a1 = Hs[r + 16][kt + k];
#pragma unroll
            for (int j = 0; j < 16; ++j) {
                float b = B1s[k][cb * 16 + j];
                acc[0][j] = fmaf(a0, b, acc[0][j]);
                acc[1][j] = fmaf(a1, b, acc[1][j]);
            }
        }
        __syncthreads();
    }
#pragma unroll
    for (int i = 0; i < 2; ++i)
#pragma unroll
        for (int j = 0; j < 16; ++j) {
            int col = cb * 16 + j;
            Ts[r + i * 16][col] = fmaxf(acc[i][j] + b1[col], 0.f);
        }

    // phase B: out = h + T @ W2 + b2, KT=32
    float acc2[2][8];
#pragma unroll
    for (int i = 0; i < 2; ++i)
#pragma unroll
        for (int j = 0; j < 8; ++j) acc2[i][j] = 0.f;

    for (int kt = 0; kt < 256; kt += 32) {
#pragma unroll
        for (int u0 = 0; u0 < 4; ++u0) {
            int u = u0 * 256 + tid;
            int kk = u >> 5, cc = (u & 31) * 4;
            *(float4*)&B2s[kk][cc] = *(const float4*)&W2[(kt + kk) * 128 + cc];
        }
        __syncthreads();
#pragma unroll
        for (int k = 0; k < 32; ++k) {
            float a0 = Ts[r][kt + k], a1 = Ts[r + 16][kt + k];
#pragma unroll
            for (int j = 0; j < 8; ++j) {
                float b = B2s[k][cb * 8 + j];
                acc2[0][j] = fmaf(a0, b, acc2[0][j]);
                acc2[1][j] = fmaf(a1, b, acc2[1][j]);
            }
        }
        __syncthreads();
    }
#pragma unroll
    for (int i = 0; i < 2; ++i) {
        int row = row0 + r + i * 16;
#pragma unroll
        for (int j = 0; j < 8; ++j) {
            int col = cb * 8 + j;
            out[(size_t)row * 128 + col] = Hs[r + i * 16][col] + acc2[i][j] + b2[col];
        }
    }
}

extern "C" void kernel_launch(void* const* d_in, const int* in_sizes, int n_in,
                              void* d_out, int out_size, void* d_ws, size_t ws_size,
                              hipStream_t stream)
{
    const float* q  = (const float*)d_in[0];
    // d_in[1] = k : dead (per-node q·k dot is segment-constant, cancels in softmax)
    const float* v  = (const float*)d_in[2];
    const float* ef = (const float*)d_in[3];
    const float* H  = (const float*)d_in[4];
    // d_in[5] = Wq, d_in[6] = Wk : dead
    const float* Wv = (const float*)d_in[7];
    const float* We = (const float*)d_in[8];
    const float* be = (const float*)d_in[9];
    const float* Wo = (const float*)d_in[10];
    const float* W1 = (const float*)d_in[11];
    const float* b1 = (const float*)d_in[12];
    const float* W2 = (const float*)d_in[13];
    const float* b2 = (const float*)d_in[14];
    float* out = (float*)d_out;

    char* w = (char*)d_ws;
    auto carve = [&](size_t bytes) -> void* {
        void* p = (void*)w;
        w += (bytes + 255) & ~(size_t)255;
        return p;
    };
    int* edge_cnt   = (int*)carve(N_EDGES * 4);                    // zeroed
    int* node_cnt   = (int*)carve(N_NODES * 4);                    // zeroed
    size_t zero_bytes = (size_t)(w - (char*)d_ws);
    int* edge_nodes = (int*)carve((size_t)N_EDGES * MAXD * 4);
    int* node_edges = (int*)carve((size_t)N_NODES * NODE_CAP * 4);
    float* pe       = (float*)carve((size_t)N_NODES * 8 * 4);
    float* eexp     = (float*)carve((size_t)N_EDGES * 8 * 4);
    float* vsrc     = (float*)carve((size_t)N_NODES * 128 * 4);
    uint4* u4       = (uint4*)carve((size_t)N_NODES * 128 * 2);    // bf16
    uint4* msgo4    = (uint4*)carve((size_t)N_EDGES * 128 * 2);    // bf16
    (void)ws_size; (void)in_sizes; (void)n_in; (void)out_size;

    hipMemsetAsync(d_ws, 0, zero_bytes, stream);

    phase1_k<<<SCAN_BLKS + GEMM_BLKS + PE_BLKS, 256, 0, stream>>>(
        v, Wv, ef, We, H, edge_cnt, edge_nodes, node_cnt, node_edges, vsrc, pe);
    eexp_k<<<(N_EDGES * 8) / 256, 256, 0, stream>>>(edge_cnt, edge_nodes, pe, be, eexp);
    zu_k<<<(N_NODES * 8) / 256, 256, 0, stream>>>(node_cnt, node_edges, eexp, vsrc, u4);
    msgwo_k<<<N_EDGES / 16, 256, 0, stream>>>(edge_cnt, edge_nodes, eexp, u4, Wo, msgo4);
    ffn_agg_k<<<N_NODES / 32, 256, 0, stream>>>(q, node_cnt, node_edges, msgo4,
                                                W1, b1, W2, b2, out);
}

// Round 11
// 276.760 us; speedup vs baseline: 2.1731x; 1.0656x over previous
//
#include <hip/hip_runtime.h>

#define N_NODES 16384
#define N_EDGES 8192
#define MAXD 32
#define NODE_CAP 64

#define SCAN_BLKS 4096
#define SCAN_T (SCAN_BLKS * 256u)      // 1,048,576 threads, 32 f4/thread
#define GEMM_BLKS 512
#define PE_BLKS 256

// ---- bf16 helpers (RNE) ----
__device__ __forceinline__ unsigned f2b(float f) {
    unsigned u = __float_as_uint(f);
    return (u + 0x7FFFu + ((u >> 16) & 1u)) >> 16;
}
__device__ __forceinline__ unsigned pack2(float lo, float hi) {
    return f2b(lo) | (f2b(hi) << 16);
}
__device__ __forceinline__ float blo(unsigned w) { return __uint_as_float(w << 16); }
__device__ __forceinline__ float bhi(unsigned w) { return __uint_as_float(w & 0xFFFF0000u); }

// ---- scan one uint4 of H at flat float4-index i ----
__device__ __forceinline__ void scan_u4(int* __restrict__ edge_cnt,
    int* __restrict__ edge_nodes, int* __restrict__ node_cnt,
    int* __restrict__ node_edges, uint4 x, unsigned i)
{
    if (!(x.x | x.y | x.z | x.w)) return;
    unsigned base = i * 4u;
    int n  = (int)(base >> 13);          // 8192 floats per H row
    int e0 = (int)(base & 8191u);
    int m = (x.x ? 1 : 0) | (x.y ? 2 : 0) | (x.z ? 4 : 0) | (x.w ? 8 : 0);
    int np = atomicAdd(&node_cnt[n], __popc(m));
    if (x.x) { int p = atomicAdd(&edge_cnt[e0+0], 1); if (p < MAXD) edge_nodes[(e0+0)*MAXD+p] = n;
               if (np < NODE_CAP) node_edges[n*NODE_CAP+np] = e0+0; ++np; }
    if (x.y) { int p = atomicAdd(&edge_cnt[e0+1], 1); if (p < MAXD) edge_nodes[(e0+1)*MAXD+p] = n;
               if (np < NODE_CAP) node_edges[n*NODE_CAP+np] = e0+1; ++np; }
    if (x.z) { int p = atomicAdd(&edge_cnt[e0+2], 1); if (p < MAXD) edge_nodes[(e0+2)*MAXD+p] = n;
               if (np < NODE_CAP) node_edges[n*NODE_CAP+np] = e0+2; ++np; }
    if (x.w) { int p = atomicAdd(&edge_cnt[e0+3], 1); if (p < MAXD) edge_nodes[(e0+3)*MAXD+p] = n;
               if (np < NODE_CAP) node_edges[n*NODE_CAP+np] = e0+3; ++np; }
}

// ---------------- scan_k: standalone, lean-VGPR (R8-probe structure) ----------------
__global__ __launch_bounds__(256, 8) void scan_k(const float* __restrict__ H,
    int* __restrict__ edge_cnt, int* __restrict__ edge_nodes,
    int* __restrict__ node_cnt, int* __restrict__ node_edges)
{
    const unsigned g = blockIdx.x * 256u + threadIdx.x;
    const unsigned T = SCAN_T;
    const uint4* H4 = (const uint4*)H;
#pragma unroll 1
    for (int it = 0; it < 32; it += 4) {
        unsigned i0 = (unsigned)(it + 0) * T + g;
        unsigned i1 = (unsigned)(it + 1) * T + g;
        unsigned i2 = (unsigned)(it + 2) * T + g;
        unsigned i3 = (unsigned)(it + 3) * T + g;
        uint4 x0 = H4[i0];
        uint4 x1 = H4[i1];
        uint4 x2 = H4[i2];
        uint4 x3 = H4[i3];
        scan_u4(edge_cnt, edge_nodes, node_cnt, node_edges, x0, i0);
        scan_u4(edge_cnt, edge_nodes, node_cnt, node_edges, x1, i1);
        scan_u4(edge_cnt, edge_nodes, node_cnt, node_edges, x2, i2);
        scan_u4(edge_cnt, edge_nodes, node_cnt, node_edges, x3, i3);
    }
}

// ---------------- vwe_k: vsrc = v @ Wv (no LDS) ∥ pe = ef @ We ----------------
__global__ __launch_bounds__(256) void vwe_k(
    const float* __restrict__ v, const float* __restrict__ Wv,
    const float* __restrict__ ef, const float* __restrict__ We,
    float* __restrict__ vsrc, float* __restrict__ pe)
{
    const int b = blockIdx.x, tid = threadIdx.x;
    if (b < GEMM_BLKS) {
        const int row0 = b * 32;
        const int r  = tid >> 4;
        const int c0 = (tid & 15) * 8;
        const float4* A4 = (const float4*)v;
        const float4* B4 = (const float4*)Wv;
        float acc[2][8];
#pragma unroll
        for (int i = 0; i < 2; ++i)
#pragma unroll
            for (int j = 0; j < 8; ++j) acc[i][j] = 0.f;
#pragma unroll 4
        for (int k4 = 0; k4 < 32; ++k4) {
            float4 a0 = A4[(size_t)(row0 + r) * 32 + k4];
            float4 a1 = A4[(size_t)(row0 + r + 16) * 32 + k4];
#pragma unroll
            for (int kk = 0; kk < 4; ++kk) {
                int k = k4 * 4 + kk;
                float4 b0 = B4[k * 32 + (c0 >> 2)];
                float4 b1 = B4[k * 32 + (c0 >> 2) + 1];
                float av0 = kk == 0 ? a0.x : kk == 1 ? a0.y : kk == 2 ? a0.z : a0.w;
                float av1 = kk == 0 ? a1.x : kk == 1 ? a1.y : kk == 2 ? a1.z : a1.w;
                acc[0][0] = fmaf(av0, b0.x, acc[0][0]); acc[0][1] = fmaf(av0, b0.y, acc[0][1]);
                acc[0][2] = fmaf(av0, b0.z, acc[0][2]); acc[0][3] = fmaf(av0, b0.w, acc[0][3]);
                acc[0][4] = fmaf(av0, b1.x, acc[0][4]); acc[0][5] = fmaf(av0, b1.y, acc[0][5]);
                acc[0][6] = fmaf(av0, b1.z, acc[0][6]); acc[0][7] = fmaf(av0, b1.w, acc[0][7]);
                acc[1][0] = fmaf(av1, b0.x, acc[1][0]); acc[1][1] = fmaf(av1, b0.y, acc[1][1]);
                acc[1][2] = fmaf(av1, b0.z, acc[1][2]); acc[1][3] = fmaf(av1, b0.w, acc[1][3]);
                acc[1][4] = fmaf(av1, b1.x, acc[1][4]); acc[1][5] = fmaf(av1, b1.y, acc[1][5]);
                acc[1][6] = fmaf(av1, b1.z, acc[1][6]); acc[1][7] = fmaf(av1, b1.w, acc[1][7]);
            }
        }
#pragma unroll
        for (int i = 0; i < 2; ++i) {
            int row = row0 + r + i * 16;
            float4 o0 = {acc[i][0], acc[i][1], acc[i][2], acc[i][3]};
            float4 o1 = {acc[i][4], acc[i][5], acc[i][6], acc[i][7]};
            *(float4*)&vsrc[(size_t)row * 128 + c0]     = o0;
            *(float4*)&vsrc[(size_t)row * 128 + c0 + 4] = o1;
        }
    } else {
        int base = (b - GEMM_BLKS) * 512 + tid;
#pragma unroll
        for (int t = 0; t < 2; ++t) {
            int g = base + t * 256;
            int n = g >> 3, h = g & 7;
            const float4* ef4 = (const float4*)ef + n * 16;
            float p = 0.f;
#pragma unroll
            for (int d4 = 0; d4 < 16; ++d4) {
                float4 x = ef4[d4];
                p += x.x * We[(d4 * 4 + 0) * 8 + h] + x.y * We[(d4 * 4 + 1) * 8 + h]
                   + x.z * We[(d4 * 4 + 2) * 8 + h] + x.w * We[(d4 * 4 + 3) * 8 + h];
            }
            pe[g] = p;
        }
    }
}

// ---------------- eexp[e,h] = exp(be[h] + sum_j pe[n_j,h])  (4-way ILP) ----------------
__global__ __launch_bounds__(256) void eexp_k(const int* __restrict__ edge_cnt,
    const int* __restrict__ edge_nodes, const float* __restrict__ pe,
    const float* __restrict__ be, float* __restrict__ eexp)
{
    int g = blockIdx.x * 256 + threadIdx.x;   // (e,h)
    int e = g >> 3, h = g & 7;
    int cnt = min(edge_cnt[e], MAXD);
    float s0 = be[h], s1 = 0.f, s2 = 0.f, s3 = 0.f;
    int j = 0;
    for (; j + 4 <= cnt; j += 4) {
        int4 nn = *(const int4*)&edge_nodes[e * MAXD + j];
        s0 += pe[nn.x * 8 + h];
        s1 += pe[nn.y * 8 + h];
        s2 += pe[nn.z * 8 + h];
        s3 += pe[nn.w * 8 + h];
    }
    for (; j < cnt; ++j) s0 += pe[edge_nodes[e * MAXD + j] * 8 + h];
    eexp[g] = __expf((s0 + s1) + (s2 + s3));  // softmax shift-invariant; |s|=O(1) safe
}

// ---- zu_k: z[n,h] = sum eexp; u[n, h*16..+16) = (1/(z+eps)) * vsrc, stored bf16 ----
__global__ __launch_bounds__(256) void zu_k(const int* __restrict__ node_cnt,
    const int* __restrict__ node_edges, const float* __restrict__ eexp,
    const float* __restrict__ vsrc, uint4* __restrict__ u4)
{
    int g = blockIdx.x * 256 + threadIdx.x;   // (n,h)
    int n = g >> 3, h = g & 7;
    int cnt = min(node_cnt[n], NODE_CAP);
    float z0 = 0.f, z1 = 0.f, z2 = 0.f, z3 = 0.f;
    int i = 0;
    for (; i + 4 <= cnt; i += 4) {
        int4 ee = *(const int4*)&node_edges[n * NODE_CAP + i];
        z0 += eexp[ee.x * 8 + h];
        z1 += eexp[ee.y * 8 + h];
        z2 += eexp[ee.z * 8 + h];
        z3 += eexp[ee.w * 8 + h];
    }
    for (; i < cnt; ++i) z0 += eexp[node_edges[n * NODE_CAP + i] * 8 + h];
    float s = 1.0f / (((z0 + z1) + (z2 + z3)) + 1e-10f);

    const float4* v4 = (const float4*)vsrc + (size_t)n * 32 + h * 4;
    float4 x0 = v4[0], x1 = v4[1], x2 = v4[2], x3 = v4[3];
    uint4 w0, w1;
    w0.x = pack2(s * x0.x, s * x0.y); w0.y = pack2(s * x0.z, s * x0.w);
    w0.z = pack2(s * x1.x, s * x1.y); w0.w = pack2(s * x1.z, s * x1.w);
    w1.x = pack2(s * x2.x, s * x2.y); w1.y = pack2(s * x2.z, s * x2.w);
    w1.z = pack2(s * x3.x, s * x3.y); w1.w = pack2(s * x3.z, s * x3.w);
    u4[(size_t)n * 16 + h * 2]     = w0;
    u4[(size_t)n * 16 + h * 2 + 1] = w1;
}

// ---- fused msg+Wo: msg[e,c] = eexp[e,h] * sum_j u[n_j,c]; msgo = msg @ Wo (bf16 out) ----
__global__ __launch_bounds__(256) void msgwo_k(const int* __restrict__ edge_cnt,
    const int* __restrict__ edge_nodes, const float* __restrict__ eexp,
    const uint4* __restrict__ u4, const float* __restrict__ Wo,
    uint4* __restrict__ msgo4)
{
    __shared__ float Ms[16][128];
    __shared__ float Bs[32][128];
    const int tid = threadIdx.x;
    const int e0  = blockIdx.x * 16;

    {   // one (le, c8) item per thread: 8 channels, all within head h = c8>>1
        int le = tid >> 4, c8 = tid & 15;
        int e = e0 + le;
        int h = c8 >> 1;
        int cnt = min(edge_cnt[e], MAXD);
        float eh = eexp[e * 8 + h];
        float a[8];
#pragma unroll
        for (int k = 0; k < 8; ++k) a[k] = 0.f;
        int j = 0;
        for (; j + 4 <= cnt; j += 4) {
            int4 nn = *(const int4*)&edge_nodes[e * MAXD + j];
            uint4 w0 = u4[(size_t)nn.x * 16 + c8];
            uint4 w1 = u4[(size_t)nn.y * 16 + c8];
            uint4 w2 = u4[(size_t)nn.z * 16 + c8];
            uint4 w3 = u4[(size_t)nn.w * 16 + c8];
            a[0] += (blo(w0.x) + blo(w1.x)) + (blo(w2.x) + blo(w3.x));
            a[1] += (bhi(w0.x) + bhi(w1.x)) + (bhi(w2.x) + bhi(w3.x));
            a[2] += (blo(w0.y) + blo(w1.y)) + (blo(w2.y) + blo(w3.y));
            a[3] += (bhi(w0.y) + bhi(w1.y)) + (bhi(w2.y) + bhi(w3.y));
            a[4] += (blo(w0.z) + blo(w1.z)) + (blo(w2.z) + blo(w3.z));
            a[5] += (bhi(w0.z) + bhi(w1.z)) + (bhi(w2.z) + bhi(w3.z));
            a[6] += (blo(w0.w) + blo(w1.w)) + (blo(w2.w) + blo(w3.w));
            a[7] += (bhi(w0.w) + bhi(w1.w)) + (bhi(w2.w) + bhi(w3.w));
        }
        for (; j < cnt; ++j) {
            uint4 w = u4[(size_t)edge_nodes[e * MAXD + j] * 16 + c8];
            a[0] += blo(w.x); a[1] += bhi(w.x); a[2] += blo(w.y); a[3] += bhi(w.y);
            a[4] += blo(w.z); a[5] += bhi(w.z); a[6] += blo(w.w); a[7] += bhi(w.w);
        }
        float4 o0 = {a[0]*eh, a[1]*eh, a[2]*eh, a[3]*eh};
        float4 o1 = {a[4]*eh, a[5]*eh, a[6]*eh, a[7]*eh};
        *(float4*)&Ms[le][c8 * 8]     = o0;
        *(float4*)&Ms[le][c8 * 8 + 4] = o1;
    }
    __syncthreads();

    // msgo[e0..e0+16][:] = Ms @ Wo, bf16 out
    const int r  = tid >> 4;          // 0..15
    const int c0 = (tid & 15) * 8;
    float acc[8];
#pragma unroll
    for (int j = 0; j < 8; ++j) acc[j] = 0.f;

    for (int kt = 0; kt < 128; kt += 32) {
#pragma unroll
        for (int u0 = 0; u0 < 4; ++u0) {              // Bs: 32x128 = 1024 float4
            int u = u0 * 256 + tid;
            int kk = u >> 5, cc = (u & 31) * 4;
            *(float4*)&Bs[kk][cc] = *(const float4*)&Wo[(kt + kk) * 128 + cc];
        }
        __syncthreads();
#pragma unroll
        for (int k = 0; k < 32; ++k) {
            float a = Ms[r][kt + k];
#pragma unroll
            for (int j = 0; j < 8; ++j)
                acc[j] = fmaf(a, Bs[k][c0 + j], acc[j]);
        }
        __syncthreads();
    }
    uint4 w;
    w.x = pack2(acc[0], acc[1]); w.y = pack2(acc[2], acc[3]);
    w.z = pack2(acc[4], acc[5]); w.w = pack2(acc[6], acc[7]);
    msgo4[(size_t)(e0 + r) * 16 + (c0 >> 3)] = w;
}

// ---- final fused: h = q + sum_{e in n} msgo[e] ; out = h + relu(h@W1+b1)@W2 + b2 ----
__global__ __launch_bounds__(256) void ffn_agg_k(const float* __restrict__ q,
    const int* __restrict__ node_cnt, const int* __restrict__ node_edges,
    const uint4* __restrict__ msgo4, const float* __restrict__ W1,
    const float* __restrict__ b1, const float* __restrict__ W2,
    const float* __restrict__ b2, float* __restrict__ out)
{
    __shared__ float Hs[32][128];
    __shared__ char dyn[49152];
    float (*B1s)[256] = (float(*)[256])dyn;
    float (*Ts)[256]  = (float(*)[256])dyn;
    float (*B2s)[128] = (float(*)[128])(dyn + 32768);

    const int tid  = threadIdx.x;
    const int row0 = blockIdx.x * 32;

    {   // aggregate: Hs = q + sum msgo (bf16 gathers, 2-edge ILP x 2 uint4)
        int r = tid >> 3, lc = tid & 7;           // 16 channels: [lc*16, lc*16+16)
        int n = row0 + r;
        const float4* q4 = (const float4*)q + (size_t)n * 32 + lc * 4;
        float a[16];
        {
            float4 qa = q4[0], qb = q4[1], qc = q4[2], qd = q4[3];
            a[0]=qa.x; a[1]=qa.y; a[2]=qa.z; a[3]=qa.w;
            a[4]=qb.x; a[5]=qb.y; a[6]=qb.z; a[7]=qb.w;
            a[8]=qc.x; a[9]=qc.y; a[10]=qc.z; a[11]=qc.w;
            a[12]=qd.x; a[13]=qd.y; a[14]=qd.z; a[15]=qd.w;
        }
        int cnt = min(node_cnt[n], NODE_CAP);
        int i = 0;
        for (; i + 2 <= cnt; i += 2) {
            int ea = node_edges[n * NODE_CAP + i];
            int eb = node_edges[n * NODE_CAP + i + 1];
            uint4 wa0 = msgo4[(size_t)ea * 16 + lc * 2];
            uint4 wa1 = msgo4[(size_t)ea * 16 + lc * 2 + 1];
            uint4 wb0 = msgo4[(size_t)eb * 16 + lc * 2];
            uint4 wb1 = msgo4[(size_t)eb * 16 + lc * 2 + 1];
            a[0]  += blo(wa0.x) + blo(wb0.x); a[1]  += bhi(wa0.x) + bhi(wb0.x);
            a[2]  += blo(wa0.y) + blo(wb0.y); a[3]  += bhi(wa0.y) + bhi(wb0.y);
            a[4]  += blo(wa0.z) + blo(wb0.z); a[5]  += bhi(wa0.z) + bhi(wb0.z);
            a[6]  += blo(wa0.w) + blo(wb0.w); a[7]  += bhi(wa0.w) + bhi(wb0.w);
            a[8]  += blo(wa1.x) + blo(wb1.x); a[9]  += bhi(wa1.x) + bhi(wb1.x);
            a[10] += blo(wa1.y) + blo(wb1.y); a[11] += bhi(wa1.y) + bhi(wb1.y);
            a[12] += blo(wa1.z) + blo(wb1.z); a[13] += bhi(wa1.z) + bhi(wb1.z);
            a[14] += blo(wa1.w) + blo(wb1.w); a[15] += bhi(wa1.w) + bhi(wb1.w);
        }
        for (; i < cnt; ++i) {
            int e = node_edges[n * NODE_CAP + i];
            uint4 w0 = msgo4[(size_t)e * 16 + lc * 2];
            uint4 w1 = msgo4[(size_t)e * 16 + lc * 2 + 1];
            a[0]  += blo(w0.x); a[1]  += bhi(w0.x); a[2]  += blo(w0.y); a[3]  += bhi(w0.y);
            a[4]  += blo(w0.z); a[5]  += bhi(w0.z); a[6]  += blo(w0.w); a[7]  += bhi(w0.w);
            a[8]  += blo(w1.x); a[9]  += bhi(w1.x); a[10] += blo(w1.y); a[11] += bhi(w1.y);
            a[12] += blo(w1.z); a[13] += bhi(w1.z); a[14] += blo(w1.w); a[15] += bhi(w1.w);
        }
#pragma unroll
        for (int k = 0; k < 4; ++k) {
            float4 o = {a[k*4+0], a[k*4+1], a[k*4+2], a[k*4+3]};
            *(float4*)&Hs[r][lc * 16 + k * 4] = o;
        }
    }
    __syncthreads();

    const int r  = tid >> 4;
    const int cb = tid & 15;

    // phase A: T = relu(h @ W1 + b1), KT=32
    float acc[2][16];
#pragma unroll
    for (int i = 0; i < 2; ++i)
#pragma unroll
        for (int j = 0; j < 16; ++j) acc[i][j] = 0.f;

    for (int kt = 0; kt < 128; kt += 32) {
#pragma unroll
        for (int u0 = 0; u0 < 8; ++u0) {
            int u = u0 * 256 + tid;
            int kk = u >> 6, cc = (u & 63) * 4;
            *(float4*)&B1s[kk][cc] = *(const float4*)&W1[(kt + kk) * 256 + cc];
        }
        __syncthreads();
#pragma unroll
        for (int k = 0; k < 32; ++k) {
            float a0 = Hs[r][kt + k], a1 = Hs[r + 16][kt + k];
#pragma unroll
            for (int j = 0; j < 16; ++j) {
                float b = B1s[k][cb * 16 + j];
                acc[0][j] = fmaf(a0, b, acc[0][j]);
                acc[1][j] = fmaf(a1, b, acc[1][j]);
            }
        }
        __syncthreads();
    }
#pragma unroll
    for (int i = 0; i < 2; ++i)
#pragma unroll
        for (int j = 0; j < 16; ++j) {
            int col = cb * 16 + j;
            Ts[r + i * 16][col] = fmaxf(acc[i][j] + b1[col], 0.f);
        }

    // phase B: out = h + T @ W2 + b2, KT=32
    float acc2[2][8];
#pragma unroll
    for (int i = 0; i < 2; ++i)
#pragma unroll
        for (int j = 0; j < 8; ++j) acc2[i][j] = 0.f;

    for (int kt = 0; kt < 256; kt += 32) {
#pragma unroll
        for (int u0 = 0; u0 < 4; ++u0) {
            int u = u0 * 256 + tid;
            int kk = u >> 5, cc = (u & 31) * 4;
            *(float4*)&B2s[kk][cc] = *(const float4*)&W2[(kt + kk) * 128 + cc];
        }
        __syncthreads();
#pragma unroll
        for (int k = 0; k < 32; ++k) {
            float a0 = Ts[r][kt + k], a1 = Ts[r + 16][kt + k];
#pragma unroll
            for (int j = 0; j < 8; ++j) {
                float b = B2s[k][cb * 8 + j];
                acc2[0][j] = fmaf(a0, b, acc2[0][j]);
                acc2[1][j] = fmaf(a1, b, acc2[1][j]);
            }
        }
        __syncthreads();
    }
#pragma unroll
    for (int i = 0; i < 2; ++i) {
        int row = row0 + r + i * 16;
#pragma unroll
        for (int j = 0; j < 8; ++j) {
            int col = cb * 8 + j;
            out[(size_t)row * 128 + col] = Hs[r + i * 16][col] + acc2[i][j] + b2[col];
        }
    }
}

extern "C" void kernel_launch(void* const* d_in, const int* in_sizes, int n_in,
                              void* d_out, int out_size, void* d_ws, size_t ws_size,
                              hipStream_t stream)
{
    const float* q  = (const float*)d_in[0];
    // d_in[1] = k : dead (per-node q·k dot is segment-constant, cancels in softmax)
    const float* v  = (const float*)d_in[2];
    const float* ef = (const float*)d_in[3];
    const float* H  = (const float*)d_in[4];
    // d_in[5] = Wq, d_in[6] = Wk : dead
    const float* Wv = (const float*)d_in[7];
    const float* We = (const float*)d_in[8];
    const float* be = (const float*)d_in[9];
    const float* Wo = (const float*)d_in[10];
    const float* W1 = (const float*)d_in[11];
    const float* b1 = (const float*)d_in[12];
    const float* W2 = (const float*)d_in[13];
    const float* b2 = (const float*)d_in[14];
    float* out = (float*)d_out;

    char* w = (char*)d_ws;
    auto carve = [&](size_t bytes) -> void* {
        void* p = (void*)w;
        w += (bytes + 255) & ~(size_t)255;
        return p;
    };
    int* edge_cnt   = (int*)carve(N_EDGES * 4);                    // zeroed
    int* node_cnt   = (int*)carve(N_NODES * 4);                    // zeroed
    size_t zero_bytes = (size_t)(w - (char*)d_ws);
    int* edge_nodes = (int*)carve((size_t)N_EDGES * MAXD * 4);
    int* node_edges = (int*)carve((size_t)N_NODES * NODE_CAP * 4);
    float* pe       = (float*)carve((size_t)N_NODES * 8 * 4);
    float* eexp     = (float*)carve((size_t)N_EDGES * 8 * 4);
    float* vsrc     = (float*)carve((size_t)N_NODES * 128 * 4);
    uint4* u4       = (uint4*)carve((size_t)N_NODES * 128 * 2);    // bf16
    uint4* msgo4    = (uint4*)carve((size_t)N_EDGES * 128 * 2);    // bf16
    (void)ws_size; (void)in_sizes; (void)n_in; (void)out_size;

    hipMemsetAsync(d_ws, 0, zero_bytes, stream);

    scan_k<<<SCAN_BLKS, 256, 0, stream>>>(H, edge_cnt, edge_nodes, node_cnt, node_edges);
    vwe_k<<<GEMM_BLKS + PE_BLKS, 256, 0, stream>>>(v, Wv, ef, We, vsrc, pe);
    eexp_k<<<(N_EDGES * 8) / 256, 256, 0, stream>>>(edge_cnt, edge_nodes, pe, be, eexp);
    zu_k<<<(N_NODES * 8) / 256, 256, 0, stream>>>(node_cnt, node_edges, eexp, vsrc, u4);
    msgwo_k<<<N_EDGES / 16, 256, 0, stream>>>(edge_cnt, edge_nodes, eexp, u4, Wo, msgo4);
    ffn_agg_k<<<N_NODES / 32, 256, 0, stream>>>(q, node_cnt, node_edges, msgo4,
                                                W1, b1, W2, b2, out);
}